// Round 1
// baseline (1994.552 us; speedup 1.0000x reference)
//
#include <hip/hip_runtime.h>

#define NN 100000
#define EE 1200000

// ---------------- degree / dinv ----------------
__global__ __launch_bounds__(256) void k_deg_init(float* __restrict__ deg) {
  int i = blockIdx.x * 256 + threadIdx.x;
  if (i < NN) deg[i] = 1.0f;  // self-loop contributes 1
}

__global__ __launch_bounds__(256) void k_deg_count(const int* __restrict__ col, float* __restrict__ deg) {
  int i = blockIdx.x * 256 + threadIdx.x;
  if (i < EE) unsafeAtomicAdd(&deg[col[i]], 1.0f);
}

__global__ __launch_bounds__(256) void k_dinv(float* __restrict__ deg) {
  int i = blockIdx.x * 256 + threadIdx.x;
  if (i < NN) deg[i] = rsqrtf(deg[i]);  // deg >= 1 always
}

// ---------------- GEMM1: g = (x @ W1) * dinv[row]; acc = g ----------------
// x [NN,128] @ W [128,64]. Block: 64 rows, 256 threads, 4x4 register tile.
__global__ __launch_bounds__(256) void k_gemm1(const float* __restrict__ x, const float* __restrict__ W,
                                               const float* __restrict__ dinv,
                                               float* __restrict__ g, float* __restrict__ acc) {
  __shared__ __align__(16) float Ws[128 * 64];   // 32 KB
  __shared__ __align__(16) float xs[64][68];     // [k within chunk][row], 17 KB, stride 68 -> conflict-free reads
  const int t = threadIdx.x;
  const int row0 = blockIdx.x * 64;

  // load all of W (8192 floats, float4-coalesced)
  #pragma unroll
  for (int p = 0; p < 8; ++p) {
    int i = (t + p * 256) * 4;
    *reinterpret_cast<float4*>(&Ws[i]) = *reinterpret_cast<const float4*>(&W[i]);
  }

  const int rq = t >> 4;   // 0..15 -> rows rq*4 .. rq*4+3
  const int cq = t & 15;   // cols cq*4 .. cq*4+3
  float a[4][4];
  #pragma unroll
  for (int i = 0; i < 4; ++i)
    #pragma unroll
    for (int j = 0; j < 4; ++j) a[i][j] = 0.0f;

  for (int kc = 0; kc < 2; ++kc) {   // two K-chunks of 64
    __syncthreads();
    // stage x chunk transposed into LDS
    #pragma unroll
    for (int p = 0; p < 4; ++p) {
      int idx = t + p * 256;          // 0..1023
      int r = idx >> 4;               // 0..63
      int k4 = (idx & 15) << 2;       // 0..60
      int grow = row0 + r;
      float4 v = make_float4(0.f, 0.f, 0.f, 0.f);
      if (grow < NN) v = *reinterpret_cast<const float4*>(&x[(size_t)grow * 128 + kc * 64 + k4]);
      xs[k4 + 0][r] = v.x;
      xs[k4 + 1][r] = v.y;
      xs[k4 + 2][r] = v.z;
      xs[k4 + 3][r] = v.w;
    }
    __syncthreads();
    #pragma unroll 8
    for (int k = 0; k < 64; ++k) {
      float4 xv = *reinterpret_cast<const float4*>(&xs[k][rq * 4]);
      float4 wv = *reinterpret_cast<const float4*>(&Ws[(kc * 64 + k) * 64 + cq * 4]);
      a[0][0] = fmaf(xv.x, wv.x, a[0][0]); a[0][1] = fmaf(xv.x, wv.y, a[0][1]);
      a[0][2] = fmaf(xv.x, wv.z, a[0][2]); a[0][3] = fmaf(xv.x, wv.w, a[0][3]);
      a[1][0] = fmaf(xv.y, wv.x, a[1][0]); a[1][1] = fmaf(xv.y, wv.y, a[1][1]);
      a[1][2] = fmaf(xv.y, wv.z, a[1][2]); a[1][3] = fmaf(xv.y, wv.w, a[1][3]);
      a[2][0] = fmaf(xv.z, wv.x, a[2][0]); a[2][1] = fmaf(xv.z, wv.y, a[2][1]);
      a[2][2] = fmaf(xv.z, wv.z, a[2][2]); a[2][3] = fmaf(xv.z, wv.w, a[2][3]);
      a[3][0] = fmaf(xv.w, wv.x, a[3][0]); a[3][1] = fmaf(xv.w, wv.y, a[3][1]);
      a[3][2] = fmaf(xv.w, wv.z, a[3][2]); a[3][3] = fmaf(xv.w, wv.w, a[3][3]);
    }
  }
  #pragma unroll
  for (int i = 0; i < 4; ++i) {
    int grow = row0 + rq * 4 + i;
    if (grow < NN) {
      float dv = dinv[grow];
      float4 v = make_float4(a[i][0] * dv, a[i][1] * dv, a[i][2] * dv, a[i][3] * dv);
      *reinterpret_cast<float4*>(&g[(size_t)grow * 64 + cq * 4]) = v;
      *reinterpret_cast<float4*>(&acc[(size_t)grow * 64 + cq * 4]) = v;
    }
  }
}

// ---------------- scatter layer1: acc[col] += g[row], 64 feats, 16 thr/edge ----------------
__global__ __launch_bounds__(256) void k_scatter1(const int* __restrict__ row, const int* __restrict__ col,
                                                  const float* __restrict__ g, float* __restrict__ acc) {
  int i = blockIdx.x * 256 + threadIdx.x;      // < EE*16 = 19.2M
  if (i >= EE * 16) return;
  int e = i >> 4;
  int q = (i & 15) << 2;
  int r = row[e], c = col[e];
  float4 v = *reinterpret_cast<const float4*>(&g[(size_t)r * 64 + q]);
  float* dst = &acc[(size_t)c * 64 + q];
  unsafeAtomicAdd(dst + 0, v.x);
  unsafeAtomicAdd(dst + 1, v.y);
  unsafeAtomicAdd(dst + 2, v.z);
  unsafeAtomicAdd(dst + 3, v.w);
}

// ---------------- epilogue1: hid = leaky_relu(acc*dinv + b1) ----------------
__global__ __launch_bounds__(256) void k_epi1(const float* __restrict__ acc, const float* __restrict__ dinv,
                                              const float* __restrict__ b1, float* __restrict__ hid) {
  int i = blockIdx.x * 256 + threadIdx.x;      // < NN*16
  if (i >= NN * 16) return;
  int n = i >> 4;
  int c4 = (i & 15) << 2;
  float dv = dinv[n];
  float4 av = *reinterpret_cast<const float4*>(&acc[(size_t)n * 64 + c4]);
  float4 bv = *reinterpret_cast<const float4*>(&b1[c4]);
  float4 o;
  o.x = av.x * dv + bv.x; o.y = av.y * dv + bv.y;
  o.z = av.z * dv + bv.z; o.w = av.w * dv + bv.w;
  o.x = o.x > 0.f ? o.x : 0.01f * o.x;
  o.y = o.y > 0.f ? o.y : 0.01f * o.y;
  o.z = o.z > 0.f ? o.z : 0.01f * o.z;
  o.w = o.w > 0.f ? o.w : 0.01f * o.w;
  *reinterpret_cast<float4*>(&hid[(size_t)n * 64 + c4]) = o;
}

// ---------------- GEMM2: g2 = (hid @ W2) * dinv[row]; acc2 = g2 ----------------
// hid [NN,64] @ W [64,40]. Block: 128 rows, 256 threads, 4 rows x 5 cols per thread.
__global__ __launch_bounds__(256) void k_gemm2(const float* __restrict__ hid, const float* __restrict__ W,
                                               const float* __restrict__ dinv,
                                               float* __restrict__ g2, float* __restrict__ acc2) {
  __shared__ __align__(16) float Ws[64 * 40];      // 10.2 KB
  __shared__ __align__(16) float xs[64][132];      // [k][row 0..127], 33.8 KB
  const int t = threadIdx.x;
  const int row0 = blockIdx.x * 128;

  for (int i = t; i < 640; i += 256)
    *reinterpret_cast<float4*>(&Ws[i * 4]) = *reinterpret_cast<const float4*>(&W[i * 4]);

  #pragma unroll
  for (int p = 0; p < 8; ++p) {
    int idx = t + p * 256;          // 0..2047
    int r = idx >> 4;               // 0..127
    int k4 = (idx & 15) << 2;       // 0..60
    int grow = row0 + r;
    float4 v = make_float4(0.f, 0.f, 0.f, 0.f);
    if (grow < NN) v = *reinterpret_cast<const float4*>(&hid[(size_t)grow * 64 + k4]);
    xs[k4 + 0][r] = v.x;
    xs[k4 + 1][r] = v.y;
    xs[k4 + 2][r] = v.z;
    xs[k4 + 3][r] = v.w;
  }
  __syncthreads();

  const int rq = t >> 3;   // 0..31 -> rows rq*4..+3
  const int cq = t & 7;    // cols cq*5..+5
  float a[4][5];
  #pragma unroll
  for (int i = 0; i < 4; ++i)
    #pragma unroll
    for (int j = 0; j < 5; ++j) a[i][j] = 0.0f;

  #pragma unroll 8
  for (int k = 0; k < 64; ++k) {
    float4 xv = *reinterpret_cast<const float4*>(&xs[k][rq * 4]);
    float w0 = Ws[k * 40 + cq * 5 + 0];
    float w1 = Ws[k * 40 + cq * 5 + 1];
    float w2 = Ws[k * 40 + cq * 5 + 2];
    float w3 = Ws[k * 40 + cq * 5 + 3];
    float w4 = Ws[k * 40 + cq * 5 + 4];
    a[0][0] = fmaf(xv.x, w0, a[0][0]); a[0][1] = fmaf(xv.x, w1, a[0][1]);
    a[0][2] = fmaf(xv.x, w2, a[0][2]); a[0][3] = fmaf(xv.x, w3, a[0][3]);
    a[0][4] = fmaf(xv.x, w4, a[0][4]);
    a[1][0] = fmaf(xv.y, w0, a[1][0]); a[1][1] = fmaf(xv.y, w1, a[1][1]);
    a[1][2] = fmaf(xv.y, w2, a[1][2]); a[1][3] = fmaf(xv.y, w3, a[1][3]);
    a[1][4] = fmaf(xv.y, w4, a[1][4]);
    a[2][0] = fmaf(xv.z, w0, a[2][0]); a[2][1] = fmaf(xv.z, w1, a[2][1]);
    a[2][2] = fmaf(xv.z, w2, a[2][2]); a[2][3] = fmaf(xv.z, w3, a[2][3]);
    a[2][4] = fmaf(xv.z, w4, a[2][4]);
    a[3][0] = fmaf(xv.w, w0, a[3][0]); a[3][1] = fmaf(xv.w, w1, a[3][1]);
    a[3][2] = fmaf(xv.w, w2, a[3][2]); a[3][3] = fmaf(xv.w, w3, a[3][3]);
    a[3][4] = fmaf(xv.w, w4, a[3][4]);
  }

  #pragma unroll
  for (int i = 0; i < 4; ++i) {
    int grow = row0 + rq * 4 + i;
    if (grow < NN) {
      float dv = dinv[grow];
      #pragma unroll
      for (int j = 0; j < 5; ++j) {
        float v = a[i][j] * dv;
        g2[(size_t)grow * 40 + cq * 5 + j] = v;
        acc2[(size_t)grow * 40 + cq * 5 + j] = v;
      }
    }
  }
}

// ---------------- scatter layer2: acc2[col] += g2[row], 40 feats, 10 thr/edge ----------------
__global__ __launch_bounds__(256) void k_scatter2(const int* __restrict__ row, const int* __restrict__ col,
                                                  const float* __restrict__ g2, float* __restrict__ acc2) {
  int i = blockIdx.x * 256 + threadIdx.x;      // < EE*10 = 12M
  if (i >= EE * 10) return;
  int e = i / 10;
  int q = (i - e * 10) * 4;
  int r = row[e], c = col[e];
  float4 v = *reinterpret_cast<const float4*>(&g2[(size_t)r * 40 + q]);
  float* dst = &acc2[(size_t)c * 40 + q];
  unsafeAtomicAdd(dst + 0, v.x);
  unsafeAtomicAdd(dst + 1, v.y);
  unsafeAtomicAdd(dst + 2, v.z);
  unsafeAtomicAdd(dst + 3, v.w);
}

// ---------------- epilogue2: out = acc2*dinv + b2 (in-place on d_out) ----------------
__global__ __launch_bounds__(256) void k_epi2(float* __restrict__ out, const float* __restrict__ dinv,
                                              const float* __restrict__ b2) {
  int i = blockIdx.x * 256 + threadIdx.x;      // < NN*10
  if (i >= NN * 10) return;
  int n = i / 10;
  int c4 = (i - n * 10) * 4;
  float dv = dinv[n];
  float4 av = *reinterpret_cast<float4*>(&out[(size_t)n * 40 + c4]);
  float4 bv = *reinterpret_cast<const float4*>(&b2[c4]);
  float4 o;
  o.x = av.x * dv + bv.x; o.y = av.y * dv + bv.y;
  o.z = av.z * dv + bv.z; o.w = av.w * dv + bv.w;
  *reinterpret_cast<float4*>(&out[(size_t)n * 40 + c4]) = o;
}

extern "C" void kernel_launch(void* const* d_in, const int* in_sizes, int n_in,
                              void* d_out, int out_size, void* d_ws, size_t ws_size,
                              hipStream_t stream) {
  const float* x  = (const float*)d_in[0];
  const int*   ei = (const int*)d_in[1];       // [2, EE] flattened: row = ei, col = ei + EE
  const float* W1 = (const float*)d_in[2];
  const float* b1 = (const float*)d_in[3];
  const float* W2 = (const float*)d_in[4];
  const float* b2 = (const float*)d_in[5];
  float* out = (float*)d_out;

  const int* row = ei;
  const int* col = ei + EE;

  // workspace layout (floats): dinv[NN] | g1/hid[NN*64] | acc1/g2[NN*64]
  float* ws   = (float*)d_ws;
  float* dinv = ws;
  float* g1   = ws + 100352;              // 16B-aligned offset
  float* acc1 = g1 + (size_t)NN * 64;
  float* hid  = g1;                        // reuse after scatter1 done
  float* g2   = acc1;                      // reuse after hid computed
  float* acc2 = out;                       // accumulate layer2 directly into d_out

  k_deg_init <<<(NN + 255) / 256, 256, 0, stream>>>(dinv);
  k_deg_count<<<(EE + 255) / 256, 256, 0, stream>>>(col, dinv);
  k_dinv     <<<(NN + 255) / 256, 256, 0, stream>>>(dinv);

  k_gemm1    <<<(NN + 63) / 64, 256, 0, stream>>>(x, W1, dinv, g1, acc1);
  k_scatter1 <<<(EE * 16 + 255) / 256, 256, 0, stream>>>(row, col, g1, acc1);
  k_epi1     <<<(NN * 16 + 255) / 256, 256, 0, stream>>>(acc1, dinv, b1, hid);

  k_gemm2    <<<(NN + 127) / 128, 256, 0, stream>>>(hid, W2, dinv, g2, acc2);
  k_scatter2 <<<(EE * 10 + 255) / 256, 256, 0, stream>>>(row, col, g2, acc2);
  k_epi2     <<<(NN * 10 + 255) / 256, 256, 0, stream>>>(out, dinv, b2);
}

// Round 3
// 379.077 us; speedup vs baseline: 5.2616x; 5.2616x over previous
//
#include <hip/hip_runtime.h>

#define NN 100000
#define EE 1200000
#define SCAN_BLK 98   // ceil(NN/1024)

// ---------------- zero counts ----------------
__global__ __launch_bounds__(256) void k_zero(int* __restrict__ counts) {
  int i = blockIdx.x * 256 + threadIdx.x;
  if (i < NN) counts[i] = 0;
}

// ---------------- histogram of destination (col) ----------------
__global__ __launch_bounds__(256) void k_hist(const int* __restrict__ col, int* __restrict__ counts) {
  int i = blockIdx.x * 256 + threadIdx.x;
  if (i < EE) atomicAdd(&counts[col[i]], 1);
}

// ---------------- dinv = rsqrt(deg), deg = counts + 1 (self loop) ----------------
__global__ __launch_bounds__(256) void k_dinv(const int* __restrict__ counts, float* __restrict__ dinv) {
  int i = blockIdx.x * 256 + threadIdx.x;
  if (i < NN) dinv[i] = rsqrtf((float)counts[i] + 1.0f);
}

// ---------------- scan phase 1: per-block exclusive scan (1024 elems/block) ----------------
__global__ __launch_bounds__(256) void k_scan1(const int* __restrict__ counts,
                                               int* __restrict__ row_ptr, int* __restrict__ bsum) {
  __shared__ int sm[256];
  int t = threadIdx.x;
  int base = blockIdx.x * 1024 + t * 4;
  int c0 = 0, c1 = 0, c2 = 0, c3 = 0;
  if (base + 0 < NN) c0 = counts[base + 0];
  if (base + 1 < NN) c1 = counts[base + 1];
  if (base + 2 < NN) c2 = counts[base + 2];
  if (base + 3 < NN) c3 = counts[base + 3];
  int tsum = c0 + c1 + c2 + c3;
  sm[t] = tsum;
  __syncthreads();
  for (int off = 1; off < 256; off <<= 1) {
    int v = (t >= off) ? sm[t - off] : 0;
    __syncthreads();
    sm[t] += v;
    __syncthreads();
  }
  int texcl = sm[t] - tsum;
  if (t == 255) bsum[blockIdx.x] = sm[255];
  if (base + 0 < NN) row_ptr[base + 0] = texcl;
  if (base + 1 < NN) row_ptr[base + 1] = texcl + c0;
  if (base + 2 < NN) row_ptr[base + 2] = texcl + c0 + c1;
  if (base + 3 < NN) row_ptr[base + 3] = texcl + c0 + c1 + c2;
}

// ---------------- scan phase 2: scan of block sums (serial, tiny) ----------------
__global__ void k_scan2(const int* __restrict__ bsum, int* __restrict__ boff, int* __restrict__ row_ptr) {
  if (threadIdx.x == 0 && blockIdx.x == 0) {
    int run = 0;
    for (int i = 0; i < SCAN_BLK; ++i) { int v = bsum[i]; boff[i] = run; run += v; }
    row_ptr[NN] = run;   // == EE
  }
}

// ---------------- scan phase 3: add block offsets; init write cursors ----------------
__global__ __launch_bounds__(256) void k_scan3(int* __restrict__ row_ptr, const int* __restrict__ boff,
                                               int* __restrict__ wpos) {
  int t = threadIdx.x;
  int base = blockIdx.x * 1024 + t * 4;
  int add = boff[blockIdx.x];
  #pragma unroll
  for (int j = 0; j < 4; ++j) {
    int i = base + j;
    if (i < NN) { int v = row_ptr[i] + add; row_ptr[i] = v; wpos[i] = v; }
  }
}

// ---------------- CSR fill: src[p] = row[e], bucketed by col ----------------
__global__ __launch_bounds__(256) void k_build(const int* __restrict__ row, const int* __restrict__ col,
                                               int* __restrict__ wpos, int* __restrict__ src) {
  int e = blockIdx.x * 256 + threadIdx.x;
  if (e < EE) {
    int c = col[e];
    int p = atomicAdd(&wpos[c], 1);
    src[p] = row[e];
  }
}

// ---------------- GEMM1: g = (x @ W1) * dinv[row] ----------------
__global__ __launch_bounds__(256) void k_gemm1(const float* __restrict__ x, const float* __restrict__ W,
                                               const float* __restrict__ dinv, float* __restrict__ g) {
  __shared__ __align__(16) float Ws[128 * 64];   // 32 KB
  __shared__ __align__(16) float xs[64][68];     // transposed x chunk, conflict-free
  const int t = threadIdx.x;
  const int row0 = blockIdx.x * 64;

  #pragma unroll
  for (int p = 0; p < 8; ++p) {
    int i = (t + p * 256) * 4;
    *reinterpret_cast<float4*>(&Ws[i]) = *reinterpret_cast<const float4*>(&W[i]);
  }

  const int rq = t >> 4;
  const int cq = t & 15;
  float a[4][4];
  #pragma unroll
  for (int i = 0; i < 4; ++i)
    #pragma unroll
    for (int j = 0; j < 4; ++j) a[i][j] = 0.0f;

  for (int kc = 0; kc < 2; ++kc) {
    __syncthreads();
    #pragma unroll
    for (int p = 0; p < 4; ++p) {
      int idx = t + p * 256;
      int r = idx >> 4;
      int k4 = (idx & 15) << 2;
      int grow = row0 + r;
      float4 v = make_float4(0.f, 0.f, 0.f, 0.f);
      if (grow < NN) v = *reinterpret_cast<const float4*>(&x[(size_t)grow * 128 + kc * 64 + k4]);
      xs[k4 + 0][r] = v.x;
      xs[k4 + 1][r] = v.y;
      xs[k4 + 2][r] = v.z;
      xs[k4 + 3][r] = v.w;
    }
    __syncthreads();
    #pragma unroll 8
    for (int k = 0; k < 64; ++k) {
      float4 xv = *reinterpret_cast<const float4*>(&xs[k][rq * 4]);
      float4 wv = *reinterpret_cast<const float4*>(&Ws[(kc * 64 + k) * 64 + cq * 4]);
      a[0][0] = fmaf(xv.x, wv.x, a[0][0]); a[0][1] = fmaf(xv.x, wv.y, a[0][1]);
      a[0][2] = fmaf(xv.x, wv.z, a[0][2]); a[0][3] = fmaf(xv.x, wv.w, a[0][3]);
      a[1][0] = fmaf(xv.y, wv.x, a[1][0]); a[1][1] = fmaf(xv.y, wv.y, a[1][1]);
      a[1][2] = fmaf(xv.y, wv.z, a[1][2]); a[1][3] = fmaf(xv.y, wv.w, a[1][3]);
      a[2][0] = fmaf(xv.z, wv.x, a[2][0]); a[2][1] = fmaf(xv.z, wv.y, a[2][1]);
      a[2][2] = fmaf(xv.z, wv.z, a[2][2]); a[2][3] = fmaf(xv.z, wv.w, a[2][3]);
      a[3][0] = fmaf(xv.w, wv.x, a[3][0]); a[3][1] = fmaf(xv.w, wv.y, a[3][1]);
      a[3][2] = fmaf(xv.w, wv.z, a[3][2]); a[3][3] = fmaf(xv.w, wv.w, a[3][3]);
    }
  }
  #pragma unroll
  for (int i = 0; i < 4; ++i) {
    int grow = row0 + rq * 4 + i;
    if (grow < NN) {
      float dv = dinv[grow];
      float4 v = make_float4(a[i][0] * dv, a[i][1] * dv, a[i][2] * dv, a[i][3] * dv);
      *reinterpret_cast<float4*>(&g[(size_t)grow * 64 + cq * 4]) = v;
    }
  }
}

// ---------------- gather layer1 (fused epilogue): hid = lrelu((g[c]+Σg[src])·dinv[c] + b1) ----------------
__global__ __launch_bounds__(256) void k_gather1(const int* __restrict__ row_ptr, const int* __restrict__ src,
                                                 const float* __restrict__ g, const float* __restrict__ dinv,
                                                 const float* __restrict__ b1, float* __restrict__ hid) {
  int t = threadIdx.x;
  int node = blockIdx.x * 16 + (t >> 4);
  if (node >= NN) return;
  int q = (t & 15) << 2;
  int beg = row_ptr[node], end = row_ptr[node + 1];
  float4 acc = *reinterpret_cast<const float4*>(&g[(size_t)node * 64 + q]);   // self loop
  int e = beg;
  for (; e + 1 < end; e += 2) {
    int s0 = src[e], s1 = src[e + 1];
    float4 v0 = *reinterpret_cast<const float4*>(&g[(size_t)s0 * 64 + q]);
    float4 v1 = *reinterpret_cast<const float4*>(&g[(size_t)s1 * 64 + q]);
    acc.x += v0.x + v1.x; acc.y += v0.y + v1.y;
    acc.z += v0.z + v1.z; acc.w += v0.w + v1.w;
  }
  if (e < end) {
    int s0 = src[e];
    float4 v0 = *reinterpret_cast<const float4*>(&g[(size_t)s0 * 64 + q]);
    acc.x += v0.x; acc.y += v0.y; acc.z += v0.z; acc.w += v0.w;
  }
  float dv = dinv[node];
  float4 bv = *reinterpret_cast<const float4*>(&b1[q]);
  float4 o;
  o.x = acc.x * dv + bv.x; o.y = acc.y * dv + bv.y;
  o.z = acc.z * dv + bv.z; o.w = acc.w * dv + bv.w;
  o.x = o.x > 0.f ? o.x : 0.01f * o.x;
  o.y = o.y > 0.f ? o.y : 0.01f * o.y;
  o.z = o.z > 0.f ? o.z : 0.01f * o.z;
  o.w = o.w > 0.f ? o.w : 0.01f * o.w;
  *reinterpret_cast<float4*>(&hid[(size_t)node * 64 + q]) = o;
}

// ---------------- GEMM2: g2 = (hid @ W2) * dinv[row] ----------------
__global__ __launch_bounds__(256) void k_gemm2(const float* __restrict__ hid, const float* __restrict__ W,
                                               const float* __restrict__ dinv, float* __restrict__ g2) {
  __shared__ __align__(16) float Ws[64 * 40];
  __shared__ __align__(16) float xs[64][132];
  const int t = threadIdx.x;
  const int row0 = blockIdx.x * 128;

  for (int i = t; i < 640; i += 256)
    *reinterpret_cast<float4*>(&Ws[i * 4]) = *reinterpret_cast<const float4*>(&W[i * 4]);

  #pragma unroll
  for (int p = 0; p < 8; ++p) {
    int idx = t + p * 256;
    int r = idx >> 4;
    int k4 = (idx & 15) << 2;
    int grow = row0 + r;
    float4 v = make_float4(0.f, 0.f, 0.f, 0.f);
    if (grow < NN) v = *reinterpret_cast<const float4*>(&hid[(size_t)grow * 64 + k4]);
    xs[k4 + 0][r] = v.x;
    xs[k4 + 1][r] = v.y;
    xs[k4 + 2][r] = v.z;
    xs[k4 + 3][r] = v.w;
  }
  __syncthreads();

  const int rq = t >> 3;
  const int cq = t & 7;
  float a[4][5];
  #pragma unroll
  for (int i = 0; i < 4; ++i)
    #pragma unroll
    for (int j = 0; j < 5; ++j) a[i][j] = 0.0f;

  #pragma unroll 8
  for (int k = 0; k < 64; ++k) {
    float4 xv = *reinterpret_cast<const float4*>(&xs[k][rq * 4]);
    float w0 = Ws[k * 40 + cq * 5 + 0];
    float w1 = Ws[k * 40 + cq * 5 + 1];
    float w2 = Ws[k * 40 + cq * 5 + 2];
    float w3 = Ws[k * 40 + cq * 5 + 3];
    float w4 = Ws[k * 40 + cq * 5 + 4];
    a[0][0] = fmaf(xv.x, w0, a[0][0]); a[0][1] = fmaf(xv.x, w1, a[0][1]);
    a[0][2] = fmaf(xv.x, w2, a[0][2]); a[0][3] = fmaf(xv.x, w3, a[0][3]);
    a[0][4] = fmaf(xv.x, w4, a[0][4]);
    a[1][0] = fmaf(xv.y, w0, a[1][0]); a[1][1] = fmaf(xv.y, w1, a[1][1]);
    a[1][2] = fmaf(xv.y, w2, a[1][2]); a[1][3] = fmaf(xv.y, w3, a[1][3]);
    a[1][4] = fmaf(xv.y, w4, a[1][4]);
    a[2][0] = fmaf(xv.z, w0, a[2][0]); a[2][1] = fmaf(xv.z, w1, a[2][1]);
    a[2][2] = fmaf(xv.z, w2, a[2][2]); a[2][3] = fmaf(xv.z, w3, a[2][3]);
    a[2][4] = fmaf(xv.z, w4, a[2][4]);
    a[3][0] = fmaf(xv.w, w0, a[3][0]); a[3][1] = fmaf(xv.w, w1, a[3][1]);
    a[3][2] = fmaf(xv.w, w2, a[3][2]); a[3][3] = fmaf(xv.w, w3, a[3][3]);
    a[3][4] = fmaf(xv.w, w4, a[3][4]);
  }

  #pragma unroll
  for (int i = 0; i < 4; ++i) {
    int grow = row0 + rq * 4 + i;
    if (grow < NN) {
      float dv = dinv[grow];
      #pragma unroll
      for (int j = 0; j < 5; ++j)
        g2[(size_t)grow * 40 + cq * 5 + j] = a[i][j] * dv;
    }
  }
}

// ---------------- gather layer2 (fused epilogue): out = (g2[c]+Σg2[src])·dinv[c] + b2 ----------------
__global__ __launch_bounds__(320) void k_gather2(const int* __restrict__ row_ptr, const int* __restrict__ src,
                                                 const float* __restrict__ g2, const float* __restrict__ dinv,
                                                 const float* __restrict__ b2, float* __restrict__ out) {
  int t = threadIdx.x;
  int local = t / 10;
  int grp = t - local * 10;
  int node = blockIdx.x * 32 + local;
  if (node >= NN) return;
  int q = grp * 4;
  int beg = row_ptr[node], end = row_ptr[node + 1];
  float4 acc = *reinterpret_cast<const float4*>(&g2[(size_t)node * 40 + q]);  // self loop
  int e = beg;
  for (; e + 1 < end; e += 2) {
    int s0 = src[e], s1 = src[e + 1];
    float4 v0 = *reinterpret_cast<const float4*>(&g2[(size_t)s0 * 40 + q]);
    float4 v1 = *reinterpret_cast<const float4*>(&g2[(size_t)s1 * 40 + q]);
    acc.x += v0.x + v1.x; acc.y += v0.y + v1.y;
    acc.z += v0.z + v1.z; acc.w += v0.w + v1.w;
  }
  if (e < end) {
    int s0 = src[e];
    float4 v0 = *reinterpret_cast<const float4*>(&g2[(size_t)s0 * 40 + q]);
    acc.x += v0.x; acc.y += v0.y; acc.z += v0.z; acc.w += v0.w;
  }
  float dv = dinv[node];
  float4 bv = *reinterpret_cast<const float4*>(&b2[q]);
  float4 o;
  o.x = acc.x * dv + bv.x; o.y = acc.y * dv + bv.y;
  o.z = acc.z * dv + bv.z; o.w = acc.w * dv + bv.w;
  *reinterpret_cast<float4*>(&out[(size_t)node * 40 + q]) = o;
}

extern "C" void kernel_launch(void* const* d_in, const int* in_sizes, int n_in,
                              void* d_out, int out_size, void* d_ws, size_t ws_size,
                              hipStream_t stream) {
  const float* x  = (const float*)d_in[0];
  const int*   ei = (const int*)d_in[1];       // row = ei, col = ei + EE
  const float* W1 = (const float*)d_in[2];
  const float* b1 = (const float*)d_in[3];
  const float* W2 = (const float*)d_in[4];
  const float* b2 = (const float*)d_in[5];
  float* out = (float*)d_out;

  const int* row = ei;
  const int* col = ei + EE;

  // workspace layout (4B elements)
  float* ws      = (float*)d_ws;
  float* dinv    = ws;                         // 100352
  int*   counts  = (int*)(ws + 100352);        // 100352
  int*   row_ptr = counts + 100352;            // 100352 (needs NN+1)
  int*   wpos    = row_ptr + 100352;           // 100352
  int*   bsum    = wpos + 100352;              // 128
  int*   boff    = bsum + 128;                 // 128
  int*   src     = boff + 128;                 // 1200128
  float* g1      = (float*)(src + 1200128);    // 6400000
  float* hid     = g1 + 6400000;               // 6400000
  float* g2      = g1;                         // reuse (g1 dead after gather1)

  // CSR build + dinv
  k_zero <<<(NN + 255) / 256, 256, 0, stream>>>(counts);
  k_hist <<<(EE + 255) / 256, 256, 0, stream>>>(col, counts);
  k_dinv <<<(NN + 255) / 256, 256, 0, stream>>>(counts, dinv);
  k_scan1<<<SCAN_BLK, 256, 0, stream>>>(counts, row_ptr, bsum);
  k_scan2<<<1, 64, 0, stream>>>(bsum, boff, row_ptr);
  k_scan3<<<SCAN_BLK, 256, 0, stream>>>(row_ptr, boff, wpos);
  k_build<<<(EE + 255) / 256, 256, 0, stream>>>(row, col, wpos, src);

  // layer 1
  k_gemm1  <<<(NN + 63) / 64, 256, 0, stream>>>(x, W1, dinv, g1);
  k_gather1<<<(NN + 15) / 16, 256, 0, stream>>>(row_ptr, src, g1, dinv, b1, hid);

  // layer 2
  k_gemm2  <<<(NN + 127) / 128, 256, 0, stream>>>(hid, W2, dinv, g2);
  k_gather2<<<(NN + 31) / 32, 320, 0, stream>>>(row_ptr, src, g2, dinv, b2, out);
}

// Round 4
// 278.339 us; speedup vs baseline: 7.1659x; 1.3619x over previous
//
#include <hip/hip_runtime.h>

#define NN 100000
#define EE 1200000
#define NB 391          // ceil(NN/256) buckets of 256 nodes
#define EPB 4096        // edges per block in binning kernels
#define BIN_BLK 293     // ceil(EE/EPB)

// ---------------- zero bucket counters ----------------
__global__ __launch_bounds__(256) void k_zero_b(int* __restrict__ bcnt) {
  int i = blockIdx.x * 256 + threadIdx.x;
  if (i < NB) bcnt[i] = 0;
}

// ---------------- bucket histogram (LDS-aggregated) ----------------
__global__ __launch_bounds__(256) void k_binhist(const int* __restrict__ col, int* __restrict__ bcnt) {
  __shared__ int lh[NB];
  int t = threadIdx.x;
  for (int i = t; i < NB; i += 256) lh[i] = 0;
  __syncthreads();
  int base = blockIdx.x * EPB;
  #pragma unroll
  for (int i = 0; i < 16; ++i) {
    int e = base + i * 256 + t;
    if (e < EE) atomicAdd(&lh[col[e] >> 8], 1);
  }
  __syncthreads();
  for (int i = t; i < NB; i += 256) {
    int v = lh[i];
    if (v) atomicAdd(&bcnt[i], v);
  }
}

// ---------------- scan bucket counts -> bptr, init cursors ----------------
__global__ __launch_bounds__(512) void k_binscan(const int* __restrict__ bcnt, int* __restrict__ bptr,
                                                 int* __restrict__ bcur, int* __restrict__ row_ptr) {
  __shared__ int sm[512];
  int t = threadIdx.x;
  int v = (t < NB) ? bcnt[t] : 0;
  sm[t] = v;
  __syncthreads();
  for (int off = 1; off < 512; off <<= 1) {
    int u = (t >= off) ? sm[t - off] : 0;
    __syncthreads();
    sm[t] += u;
    __syncthreads();
  }
  int excl = sm[t] - v;
  if (t < NB) { bptr[t] = excl; bcur[t] = excl; }
  if (t == 0) { bptr[NB] = EE; row_ptr[NN] = EE; }
}

// ---------------- bucket fill: binned[p] = (row, col), grouped by bucket ----------------
__global__ __launch_bounds__(256) void k_binfill(const int* __restrict__ row, const int* __restrict__ col,
                                                 int* __restrict__ bcur, int2* __restrict__ binned) {
  __shared__ int lh[NB];
  __shared__ int lbase[NB];
  int t = threadIdx.x;
  for (int i = t; i < NB; i += 256) lh[i] = 0;
  __syncthreads();
  int base = blockIdx.x * EPB;
  #pragma unroll
  for (int i = 0; i < 16; ++i) {
    int e = base + i * 256 + t;
    if (e < EE) atomicAdd(&lh[col[e] >> 8], 1);
  }
  __syncthreads();
  // reserve contiguous global ranges per bucket; reset LDS cursors
  for (int i = t; i < NB; i += 256) {
    int v = lh[i];
    lbase[i] = v ? atomicAdd(&bcur[i], v) : 0;
  }
  __syncthreads();
  for (int i = t; i < NB; i += 256) lh[i] = 0;   // reuse as local cursor
  __syncthreads();
  #pragma unroll
  for (int i = 0; i < 16; ++i) {
    int e = base + i * 256 + t;
    if (e < EE) {
      int c = col[e];
      int b = c >> 8;
      int p = lbase[b] + atomicAdd(&lh[b], 1);
      binned[p] = make_int2(row[e], c);
    }
  }
}

// ---------------- per-bucket CSR build: row_ptr, src, dinv (all bucket-local) ----------------
__global__ __launch_bounds__(256) void k_build2(const int2* __restrict__ binned, const int* __restrict__ bptr,
                                                int* __restrict__ row_ptr, int* __restrict__ src,
                                                float* __restrict__ dinv) {
  __shared__ int cnt[256];
  __shared__ int sm[256];
  __shared__ int cur[256];
  int t = threadIdx.x;
  int b = blockIdx.x;
  int nb0 = b << 8;
  int nnode = NN - nb0 < 256 ? NN - nb0 : 256;
  int ebeg = bptr[b], eend = bptr[b + 1];
  cnt[t] = 0;
  __syncthreads();
  for (int e = ebeg + t; e < eend; e += 256)
    atomicAdd(&cnt[binned[e].y - nb0], 1);
  __syncthreads();
  int v = cnt[t];
  sm[t] = v;
  __syncthreads();
  for (int off = 1; off < 256; off <<= 1) {
    int u = (t >= off) ? sm[t - off] : 0;
    __syncthreads();
    sm[t] += u;
    __syncthreads();
  }
  int excl = sm[t] - v;
  if (t < nnode) {
    row_ptr[nb0 + t] = ebeg + excl;
    dinv[nb0 + t] = rsqrtf((float)v + 1.0f);   // deg = in-count + self-loop
  }
  cur[t] = excl;
  __syncthreads();
  for (int e = ebeg + t; e < eend; e += 256) {
    int2 rc = binned[e];
    int cl = rc.y - nb0;
    int p = ebeg + atomicAdd(&cur[cl], 1);
    src[p] = rc.x;
  }
}

// ---------------- GEMM1: g = (x @ W1) * dinv[row] ----------------
__global__ __launch_bounds__(256) void k_gemm1(const float* __restrict__ x, const float* __restrict__ W,
                                               const float* __restrict__ dinv, float* __restrict__ g) {
  __shared__ __align__(16) float Ws[128 * 64];   // 32 KB
  __shared__ __align__(16) float xs[64][68];     // transposed x chunk, conflict-free
  const int t = threadIdx.x;
  const int row0 = blockIdx.x * 64;

  #pragma unroll
  for (int p = 0; p < 8; ++p) {
    int i = (t + p * 256) * 4;
    *reinterpret_cast<float4*>(&Ws[i]) = *reinterpret_cast<const float4*>(&W[i]);
  }

  const int rq = t >> 4;
  const int cq = t & 15;
  float a[4][4];
  #pragma unroll
  for (int i = 0; i < 4; ++i)
    #pragma unroll
    for (int j = 0; j < 4; ++j) a[i][j] = 0.0f;

  for (int kc = 0; kc < 2; ++kc) {
    __syncthreads();
    #pragma unroll
    for (int p = 0; p < 4; ++p) {
      int idx = t + p * 256;
      int r = idx >> 4;
      int k4 = (idx & 15) << 2;
      int grow = row0 + r;
      float4 v = make_float4(0.f, 0.f, 0.f, 0.f);
      if (grow < NN) v = *reinterpret_cast<const float4*>(&x[(size_t)grow * 128 + kc * 64 + k4]);
      xs[k4 + 0][r] = v.x;
      xs[k4 + 1][r] = v.y;
      xs[k4 + 2][r] = v.z;
      xs[k4 + 3][r] = v.w;
    }
    __syncthreads();
    #pragma unroll 8
    for (int k = 0; k < 64; ++k) {
      float4 xv = *reinterpret_cast<const float4*>(&xs[k][rq * 4]);
      float4 wv = *reinterpret_cast<const float4*>(&Ws[(kc * 64 + k) * 64 + cq * 4]);
      a[0][0] = fmaf(xv.x, wv.x, a[0][0]); a[0][1] = fmaf(xv.x, wv.y, a[0][1]);
      a[0][2] = fmaf(xv.x, wv.z, a[0][2]); a[0][3] = fmaf(xv.x, wv.w, a[0][3]);
      a[1][0] = fmaf(xv.y, wv.x, a[1][0]); a[1][1] = fmaf(xv.y, wv.y, a[1][1]);
      a[1][2] = fmaf(xv.y, wv.z, a[1][2]); a[1][3] = fmaf(xv.y, wv.w, a[1][3]);
      a[2][0] = fmaf(xv.z, wv.x, a[2][0]); a[2][1] = fmaf(xv.z, wv.y, a[2][1]);
      a[2][2] = fmaf(xv.z, wv.z, a[2][2]); a[2][3] = fmaf(xv.z, wv.w, a[2][3]);
      a[3][0] = fmaf(xv.w, wv.x, a[3][0]); a[3][1] = fmaf(xv.w, wv.y, a[3][1]);
      a[3][2] = fmaf(xv.w, wv.z, a[3][2]); a[3][3] = fmaf(xv.w, wv.w, a[3][3]);
    }
  }
  #pragma unroll
  for (int i = 0; i < 4; ++i) {
    int grow = row0 + rq * 4 + i;
    if (grow < NN) {
      float dv = dinv[grow];
      float4 v = make_float4(a[i][0] * dv, a[i][1] * dv, a[i][2] * dv, a[i][3] * dv);
      *reinterpret_cast<float4*>(&g[(size_t)grow * 64 + cq * 4]) = v;
    }
  }
}

// ---------------- gather layer1 (fused epilogue): hid = lrelu((g[c]+Σg[src])·dinv[c] + b1) ----------------
__global__ __launch_bounds__(256) void k_gather1(const int* __restrict__ row_ptr, const int* __restrict__ src,
                                                 const float* __restrict__ g, const float* __restrict__ dinv,
                                                 const float* __restrict__ b1, float* __restrict__ hid) {
  int t = threadIdx.x;
  int node = blockIdx.x * 16 + (t >> 4);
  if (node >= NN) return;
  int q = (t & 15) << 2;
  int beg = row_ptr[node], end = row_ptr[node + 1];
  float4 acc = *reinterpret_cast<const float4*>(&g[(size_t)node * 64 + q]);   // self loop
  int e = beg;
  for (; e + 3 < end; e += 4) {
    int s0 = src[e], s1 = src[e + 1], s2 = src[e + 2], s3 = src[e + 3];
    float4 v0 = *reinterpret_cast<const float4*>(&g[(size_t)s0 * 64 + q]);
    float4 v1 = *reinterpret_cast<const float4*>(&g[(size_t)s1 * 64 + q]);
    float4 v2 = *reinterpret_cast<const float4*>(&g[(size_t)s2 * 64 + q]);
    float4 v3 = *reinterpret_cast<const float4*>(&g[(size_t)s3 * 64 + q]);
    acc.x += (v0.x + v1.x) + (v2.x + v3.x);
    acc.y += (v0.y + v1.y) + (v2.y + v3.y);
    acc.z += (v0.z + v1.z) + (v2.z + v3.z);
    acc.w += (v0.w + v1.w) + (v2.w + v3.w);
  }
  for (; e < end; ++e) {
    int s0 = src[e];
    float4 v0 = *reinterpret_cast<const float4*>(&g[(size_t)s0 * 64 + q]);
    acc.x += v0.x; acc.y += v0.y; acc.z += v0.z; acc.w += v0.w;
  }
  float dv = dinv[node];
  float4 bv = *reinterpret_cast<const float4*>(&b1[q]);
  float4 o;
  o.x = acc.x * dv + bv.x; o.y = acc.y * dv + bv.y;
  o.z = acc.z * dv + bv.z; o.w = acc.w * dv + bv.w;
  o.x = o.x > 0.f ? o.x : 0.01f * o.x;
  o.y = o.y > 0.f ? o.y : 0.01f * o.y;
  o.z = o.z > 0.f ? o.z : 0.01f * o.z;
  o.w = o.w > 0.f ? o.w : 0.01f * o.w;
  *reinterpret_cast<float4*>(&hid[(size_t)node * 64 + q]) = o;
}

// ---------------- GEMM2: g2 = (hid @ W2) * dinv[row] ----------------
__global__ __launch_bounds__(256) void k_gemm2(const float* __restrict__ hid, const float* __restrict__ W,
                                               const float* __restrict__ dinv, float* __restrict__ g2) {
  __shared__ __align__(16) float Ws[64 * 40];
  __shared__ __align__(16) float xs[64][132];
  const int t = threadIdx.x;
  const int row0 = blockIdx.x * 128;

  for (int i = t; i < 640; i += 256)
    *reinterpret_cast<float4*>(&Ws[i * 4]) = *reinterpret_cast<const float4*>(&W[i * 4]);

  #pragma unroll
  for (int p = 0; p < 8; ++p) {
    int idx = t + p * 256;
    int r = idx >> 4;
    int k4 = (idx & 15) << 2;
    int grow = row0 + r;
    float4 v = make_float4(0.f, 0.f, 0.f, 0.f);
    if (grow < NN) v = *reinterpret_cast<const float4*>(&hid[(size_t)grow * 64 + k4]);
    xs[k4 + 0][r] = v.x;
    xs[k4 + 1][r] = v.y;
    xs[k4 + 2][r] = v.z;
    xs[k4 + 3][r] = v.w;
  }
  __syncthreads();

  const int rq = t >> 3;
  const int cq = t & 7;
  float a[4][5];
  #pragma unroll
  for (int i = 0; i < 4; ++i)
    #pragma unroll
    for (int j = 0; j < 5; ++j) a[i][j] = 0.0f;

  #pragma unroll 8
  for (int k = 0; k < 64; ++k) {
    float4 xv = *reinterpret_cast<const float4*>(&xs[k][rq * 4]);
    float w0 = Ws[k * 40 + cq * 5 + 0];
    float w1 = Ws[k * 40 + cq * 5 + 1];
    float w2 = Ws[k * 40 + cq * 5 + 2];
    float w3 = Ws[k * 40 + cq * 5 + 3];
    float w4 = Ws[k * 40 + cq * 5 + 4];
    a[0][0] = fmaf(xv.x, w0, a[0][0]); a[0][1] = fmaf(xv.x, w1, a[0][1]);
    a[0][2] = fmaf(xv.x, w2, a[0][2]); a[0][3] = fmaf(xv.x, w3, a[0][3]);
    a[0][4] = fmaf(xv.x, w4, a[0][4]);
    a[1][0] = fmaf(xv.y, w0, a[1][0]); a[1][1] = fmaf(xv.y, w1, a[1][1]);
    a[1][2] = fmaf(xv.y, w2, a[1][2]); a[1][3] = fmaf(xv.y, w3, a[1][3]);
    a[1][4] = fmaf(xv.y, w4, a[1][4]);
    a[2][0] = fmaf(xv.z, w0, a[2][0]); a[2][1] = fmaf(xv.z, w1, a[2][1]);
    a[2][2] = fmaf(xv.z, w2, a[2][2]); a[2][3] = fmaf(xv.z, w3, a[2][3]);
    a[2][4] = fmaf(xv.z, w4, a[2][4]);
    a[3][0] = fmaf(xv.w, w0, a[3][0]); a[3][1] = fmaf(xv.w, w1, a[3][1]);
    a[3][2] = fmaf(xv.w, w2, a[3][2]); a[3][3] = fmaf(xv.w, w3, a[3][3]);
    a[3][4] = fmaf(xv.w, w4, a[3][4]);
  }

  #pragma unroll
  for (int i = 0; i < 4; ++i) {
    int grow = row0 + rq * 4 + i;
    if (grow < NN) {
      float dv = dinv[grow];
      #pragma unroll
      for (int j = 0; j < 5; ++j)
        g2[(size_t)grow * 40 + cq * 5 + j] = a[i][j] * dv;
    }
  }
}

// ---------------- gather layer2 (fused epilogue): out = (g2[c]+Σg2[src])·dinv[c] + b2 ----------------
__global__ __launch_bounds__(320) void k_gather2(const int* __restrict__ row_ptr, const int* __restrict__ src,
                                                 const float* __restrict__ g2, const float* __restrict__ dinv,
                                                 const float* __restrict__ b2, float* __restrict__ out) {
  int t = threadIdx.x;
  int local = t / 10;
  int grp = t - local * 10;
  int node = blockIdx.x * 32 + local;
  if (node >= NN) return;
  int q = grp * 4;
  int beg = row_ptr[node], end = row_ptr[node + 1];
  float4 acc = *reinterpret_cast<const float4*>(&g2[(size_t)node * 40 + q]);  // self loop
  int e = beg;
  for (; e + 3 < end; e += 4) {
    int s0 = src[e], s1 = src[e + 1], s2 = src[e + 2], s3 = src[e + 3];
    float4 v0 = *reinterpret_cast<const float4*>(&g2[(size_t)s0 * 40 + q]);
    float4 v1 = *reinterpret_cast<const float4*>(&g2[(size_t)s1 * 40 + q]);
    float4 v2 = *reinterpret_cast<const float4*>(&g2[(size_t)s2 * 40 + q]);
    float4 v3 = *reinterpret_cast<const float4*>(&g2[(size_t)s3 * 40 + q]);
    acc.x += (v0.x + v1.x) + (v2.x + v3.x);
    acc.y += (v0.y + v1.y) + (v2.y + v3.y);
    acc.z += (v0.z + v1.z) + (v2.z + v3.z);
    acc.w += (v0.w + v1.w) + (v2.w + v3.w);
  }
  for (; e < end; ++e) {
    int s0 = src[e];
    float4 v0 = *reinterpret_cast<const float4*>(&g2[(size_t)s0 * 40 + q]);
    acc.x += v0.x; acc.y += v0.y; acc.z += v0.z; acc.w += v0.w;
  }
  float dv = dinv[node];
  float4 bv = *reinterpret_cast<const float4*>(&b2[q]);
  float4 o;
  o.x = acc.x * dv + bv.x; o.y = acc.y * dv + bv.y;
  o.z = acc.z * dv + bv.z; o.w = acc.w * dv + bv.w;
  *reinterpret_cast<float4*>(&out[(size_t)node * 40 + q]) = o;
}

extern "C" void kernel_launch(void* const* d_in, const int* in_sizes, int n_in,
                              void* d_out, int out_size, void* d_ws, size_t ws_size,
                              hipStream_t stream) {
  const float* x  = (const float*)d_in[0];
  const int*   ei = (const int*)d_in[1];       // row = ei, col = ei + EE
  const float* W1 = (const float*)d_in[2];
  const float* b1 = (const float*)d_in[3];
  const float* W2 = (const float*)d_in[4];
  const float* b2 = (const float*)d_in[5];
  float* out = (float*)d_out;

  const int* row = ei;
  const int* col = ei + EE;

  // workspace layout (4B elements)
  float* ws      = (float*)d_ws;
  float* dinv    = ws;                          // 100352
  int*   row_ptr = (int*)(ws + 100352);         // 100352 (needs NN+1)
  int*   bptr    = row_ptr + 100352;            // 512 (needs NB+1)
  int*   bcnt    = bptr + 512;                  // 512
  int*   bcur    = bcnt + 512;                  // 512
  int*   src     = bcur + 512;                  // 1200128
  float* g1      = (float*)(src + 1200128);     // 6400000
  float* hid     = g1 + 6400000;                // 6400000
  float* g2      = g1;                          // reuse (g1 dead after gather1)
  int2*  binned  = (int2*)g1;                   // 2400256 ints, aliases g1 (dead before gemm1)

  // CSR build (bucketed counting sort) + dinv
  k_zero_b <<<2, 256, 0, stream>>>(bcnt);
  k_binhist<<<BIN_BLK, 256, 0, stream>>>(col, bcnt);
  k_binscan<<<1, 512, 0, stream>>>(bcnt, bptr, bcur, row_ptr);
  k_binfill<<<BIN_BLK, 256, 0, stream>>>(row, col, bcur, binned);
  k_build2 <<<NB, 256, 0, stream>>>(binned, bptr, row_ptr, src, dinv);

  // layer 1
  k_gemm1  <<<(NN + 63) / 64, 256, 0, stream>>>(x, W1, dinv, g1);
  k_gather1<<<(NN + 15) / 16, 256, 0, stream>>>(row_ptr, src, g1, dinv, b1, hid);

  // layer 2
  k_gemm2  <<<(NN + 127) / 128, 256, 0, stream>>>(hid, W2, dinv, g2);
  k_gather2<<<(NN + 31) / 32, 320, 0, stream>>>(row_ptr, src, g2, dinv, b2, out);
}

// Round 5
// 245.740 us; speedup vs baseline: 8.1165x; 1.1327x over previous
//
#include <hip/hip_runtime.h>

#define NN 100000
#define EE 1200000
#define NB 391          // ceil(NN/256) buckets of 256 nodes
#define EPB 4096        // edges per block in binning kernels
#define BIN_BLK 293     // ceil(EE/EPB)

typedef _Float16 half4 __attribute__((ext_vector_type(4)));

// ---------------- zero bucket counters ----------------
__global__ __launch_bounds__(256) void k_zero_b(int* __restrict__ bcnt) {
  int i = blockIdx.x * 256 + threadIdx.x;
  if (i < NB) bcnt[i] = 0;
}

// ---------------- bucket histogram (LDS-aggregated) ----------------
__global__ __launch_bounds__(256) void k_binhist(const int* __restrict__ col, int* __restrict__ bcnt) {
  __shared__ int lh[NB];
  int t = threadIdx.x;
  for (int i = t; i < NB; i += 256) lh[i] = 0;
  __syncthreads();
  int base = blockIdx.x * EPB;
  #pragma unroll
  for (int i = 0; i < 16; ++i) {
    int e = base + i * 256 + t;
    if (e < EE) atomicAdd(&lh[col[e] >> 8], 1);
  }
  __syncthreads();
  for (int i = t; i < NB; i += 256) {
    int v = lh[i];
    if (v) atomicAdd(&bcnt[i], v);
  }
}

// ---------------- scan bucket counts -> bptr, init cursors ----------------
__global__ __launch_bounds__(512) void k_binscan(const int* __restrict__ bcnt, int* __restrict__ bptr,
                                                 int* __restrict__ bcur, int* __restrict__ row_ptr) {
  __shared__ int sm[512];
  int t = threadIdx.x;
  int v = (t < NB) ? bcnt[t] : 0;
  sm[t] = v;
  __syncthreads();
  for (int off = 1; off < 512; off <<= 1) {
    int u = (t >= off) ? sm[t - off] : 0;
    __syncthreads();
    sm[t] += u;
    __syncthreads();
  }
  int excl = sm[t] - v;
  if (t < NB) { bptr[t] = excl; bcur[t] = excl; }
  if (t == 0) { bptr[NB] = EE; row_ptr[NN] = EE; }
}

// ---------------- bucket fill: binned[p] = (row<<8)|(col&255), grouped by bucket ----------------
__global__ __launch_bounds__(256) void k_binfill(const int* __restrict__ row, const int* __restrict__ col,
                                                 int* __restrict__ bcur, int* __restrict__ binned) {
  __shared__ int lh[NB];
  __shared__ int lbase[NB];
  int t = threadIdx.x;
  for (int i = t; i < NB; i += 256) lh[i] = 0;
  __syncthreads();
  int base = blockIdx.x * EPB;
  #pragma unroll
  for (int i = 0; i < 16; ++i) {
    int e = base + i * 256 + t;
    if (e < EE) atomicAdd(&lh[col[e] >> 8], 1);
  }
  __syncthreads();
  // reserve contiguous global ranges per bucket; reset LDS cursors
  for (int i = t; i < NB; i += 256) {
    int v = lh[i];
    lbase[i] = v ? atomicAdd(&bcur[i], v) : 0;
  }
  __syncthreads();
  for (int i = t; i < NB; i += 256) lh[i] = 0;   // reuse as local cursor
  __syncthreads();
  #pragma unroll
  for (int i = 0; i < 16; ++i) {
    int e = base + i * 256 + t;
    if (e < EE) {
      int c = col[e];
      int b = c >> 8;
      int p = lbase[b] + atomicAdd(&lh[b], 1);
      binned[p] = (row[e] << 8) | (c & 255);
    }
  }
}

// ---------------- per-bucket CSR build: row_ptr, src, dinv (all bucket-local) ----------------
__global__ __launch_bounds__(256) void k_build2(const int* __restrict__ binned, const int* __restrict__ bptr,
                                                int* __restrict__ row_ptr, int* __restrict__ src,
                                                float* __restrict__ dinv) {
  __shared__ int cnt[256];
  __shared__ int sm[256];
  __shared__ int cur[256];
  int t = threadIdx.x;
  int b = blockIdx.x;
  int nb0 = b << 8;
  int nnode = NN - nb0 < 256 ? NN - nb0 : 256;
  int ebeg = bptr[b], eend = bptr[b + 1];
  cnt[t] = 0;
  __syncthreads();
  for (int e = ebeg + t; e < eend; e += 256)
    atomicAdd(&cnt[binned[e] & 255], 1);
  __syncthreads();
  int v = cnt[t];
  sm[t] = v;
  __syncthreads();
  for (int off = 1; off < 256; off <<= 1) {
    int u = (t >= off) ? sm[t - off] : 0;
    __syncthreads();
    sm[t] += u;
    __syncthreads();
  }
  int excl = sm[t] - v;
  if (t < nnode) {
    row_ptr[nb0 + t] = ebeg + excl;
    dinv[nb0 + t] = rsqrtf((float)v + 1.0f);   // deg = in-count + self-loop
  }
  cur[t] = excl;
  __syncthreads();
  for (int e = ebeg + t; e < eend; e += 256) {
    int rc = binned[e];
    int cl = rc & 255;
    int p = ebeg + atomicAdd(&cur[cl], 1);
    src[p] = rc >> 8;
  }
}

// ---------------- GEMM1: g = fp16((x @ W1) * dinv[row]) ----------------
__global__ __launch_bounds__(256) void k_gemm1(const float* __restrict__ x, const float* __restrict__ W,
                                               const float* __restrict__ dinv, _Float16* __restrict__ g) {
  __shared__ __align__(16) float Ws[128 * 64];   // 32 KB
  __shared__ __align__(16) float xs[64][68];     // transposed x chunk, conflict-free
  const int t = threadIdx.x;
  const int row0 = blockIdx.x * 64;

  #pragma unroll
  for (int p = 0; p < 8; ++p) {
    int i = (t + p * 256) * 4;
    *reinterpret_cast<float4*>(&Ws[i]) = *reinterpret_cast<const float4*>(&W[i]);
  }

  const int rq = t >> 4;
  const int cq = t & 15;
  float a[4][4];
  #pragma unroll
  for (int i = 0; i < 4; ++i)
    #pragma unroll
    for (int j = 0; j < 4; ++j) a[i][j] = 0.0f;

  for (int kc = 0; kc < 2; ++kc) {
    __syncthreads();
    #pragma unroll
    for (int p = 0; p < 4; ++p) {
      int idx = t + p * 256;
      int r = idx >> 4;
      int k4 = (idx & 15) << 2;
      int grow = row0 + r;
      float4 v = make_float4(0.f, 0.f, 0.f, 0.f);
      if (grow < NN) v = *reinterpret_cast<const float4*>(&x[(size_t)grow * 128 + kc * 64 + k4]);
      xs[k4 + 0][r] = v.x;
      xs[k4 + 1][r] = v.y;
      xs[k4 + 2][r] = v.z;
      xs[k4 + 3][r] = v.w;
    }
    __syncthreads();
    #pragma unroll 8
    for (int k = 0; k < 64; ++k) {
      float4 xv = *reinterpret_cast<const float4*>(&xs[k][rq * 4]);
      float4 wv = *reinterpret_cast<const float4*>(&Ws[(kc * 64 + k) * 64 + cq * 4]);
      a[0][0] = fmaf(xv.x, wv.x, a[0][0]); a[0][1] = fmaf(xv.x, wv.y, a[0][1]);
      a[0][2] = fmaf(xv.x, wv.z, a[0][2]); a[0][3] = fmaf(xv.x, wv.w, a[0][3]);
      a[1][0] = fmaf(xv.y, wv.x, a[1][0]); a[1][1] = fmaf(xv.y, wv.y, a[1][1]);
      a[1][2] = fmaf(xv.y, wv.z, a[1][2]); a[1][3] = fmaf(xv.y, wv.w, a[1][3]);
      a[2][0] = fmaf(xv.z, wv.x, a[2][0]); a[2][1] = fmaf(xv.z, wv.y, a[2][1]);
      a[2][2] = fmaf(xv.z, wv.z, a[2][2]); a[2][3] = fmaf(xv.z, wv.w, a[2][3]);
      a[3][0] = fmaf(xv.w, wv.x, a[3][0]); a[3][1] = fmaf(xv.w, wv.y, a[3][1]);
      a[3][2] = fmaf(xv.w, wv.z, a[3][2]); a[3][3] = fmaf(xv.w, wv.w, a[3][3]);
    }
  }
  #pragma unroll
  for (int i = 0; i < 4; ++i) {
    int grow = row0 + rq * 4 + i;
    if (grow < NN) {
      float dv = dinv[grow];
      half4 h;
      h.x = (_Float16)(a[i][0] * dv);
      h.y = (_Float16)(a[i][1] * dv);
      h.z = (_Float16)(a[i][2] * dv);
      h.w = (_Float16)(a[i][3] * dv);
      *reinterpret_cast<half4*>(&g[(size_t)grow * 64 + cq * 4]) = h;
    }
  }
}

// ---------------- gather layer1 (fused epilogue): hid = lrelu((g[c]+Σg[src])·dinv[c] + b1) ----------------
__global__ __launch_bounds__(256) void k_gather1(const int* __restrict__ row_ptr, const int* __restrict__ src,
                                                 const _Float16* __restrict__ g, const float* __restrict__ dinv,
                                                 const float* __restrict__ b1, float* __restrict__ hid) {
  int t = threadIdx.x;
  int node = blockIdx.x * 16 + (t >> 4);
  if (node >= NN) return;
  int q = (t & 15) << 2;
  int beg = row_ptr[node], end = row_ptr[node + 1];
  half4 sv = *reinterpret_cast<const half4*>(&g[(size_t)node * 64 + q]);   // self loop
  float4 acc = make_float4((float)sv.x, (float)sv.y, (float)sv.z, (float)sv.w);
  int e = beg;
  for (; e + 3 < end; e += 4) {
    int s0 = src[e], s1 = src[e + 1], s2 = src[e + 2], s3 = src[e + 3];
    half4 v0 = *reinterpret_cast<const half4*>(&g[(size_t)s0 * 64 + q]);
    half4 v1 = *reinterpret_cast<const half4*>(&g[(size_t)s1 * 64 + q]);
    half4 v2 = *reinterpret_cast<const half4*>(&g[(size_t)s2 * 64 + q]);
    half4 v3 = *reinterpret_cast<const half4*>(&g[(size_t)s3 * 64 + q]);
    acc.x += ((float)v0.x + (float)v1.x) + ((float)v2.x + (float)v3.x);
    acc.y += ((float)v0.y + (float)v1.y) + ((float)v2.y + (float)v3.y);
    acc.z += ((float)v0.z + (float)v1.z) + ((float)v2.z + (float)v3.z);
    acc.w += ((float)v0.w + (float)v1.w) + ((float)v2.w + (float)v3.w);
  }
  for (; e < end; ++e) {
    int s0 = src[e];
    half4 v0 = *reinterpret_cast<const half4*>(&g[(size_t)s0 * 64 + q]);
    acc.x += (float)v0.x; acc.y += (float)v0.y; acc.z += (float)v0.z; acc.w += (float)v0.w;
  }
  float dv = dinv[node];
  float4 bv = *reinterpret_cast<const float4*>(&b1[q]);
  float4 o;
  o.x = acc.x * dv + bv.x; o.y = acc.y * dv + bv.y;
  o.z = acc.z * dv + bv.z; o.w = acc.w * dv + bv.w;
  o.x = o.x > 0.f ? o.x : 0.01f * o.x;
  o.y = o.y > 0.f ? o.y : 0.01f * o.y;
  o.z = o.z > 0.f ? o.z : 0.01f * o.z;
  o.w = o.w > 0.f ? o.w : 0.01f * o.w;
  *reinterpret_cast<float4*>(&hid[(size_t)node * 64 + q]) = o;
}

// ---------------- GEMM2: g2 = fp16((hid @ W2) * dinv[row]) ----------------
__global__ __launch_bounds__(256) void k_gemm2(const float* __restrict__ hid, const float* __restrict__ W,
                                               const float* __restrict__ dinv, _Float16* __restrict__ g2) {
  __shared__ __align__(16) float Ws[64 * 40];
  __shared__ __align__(16) float xs[64][132];
  const int t = threadIdx.x;
  const int row0 = blockIdx.x * 128;

  for (int i = t; i < 640; i += 256)
    *reinterpret_cast<float4*>(&Ws[i * 4]) = *reinterpret_cast<const float4*>(&W[i * 4]);

  #pragma unroll
  for (int p = 0; p < 8; ++p) {
    int idx = t + p * 256;
    int r = idx >> 4;
    int k4 = (idx & 15) << 2;
    int grow = row0 + r;
    float4 v = make_float4(0.f, 0.f, 0.f, 0.f);
    if (grow < NN) v = *reinterpret_cast<const float4*>(&hid[(size_t)grow * 64 + k4]);
    xs[k4 + 0][r] = v.x;
    xs[k4 + 1][r] = v.y;
    xs[k4 + 2][r] = v.z;
    xs[k4 + 3][r] = v.w;
  }
  __syncthreads();

  const int rq = t >> 3;
  const int cq = t & 7;
  float a[4][5];
  #pragma unroll
  for (int i = 0; i < 4; ++i)
    #pragma unroll
    for (int j = 0; j < 5; ++j) a[i][j] = 0.0f;

  #pragma unroll 8
  for (int k = 0; k < 64; ++k) {
    float4 xv = *reinterpret_cast<const float4*>(&xs[k][rq * 4]);
    float w0 = Ws[k * 40 + cq * 5 + 0];
    float w1 = Ws[k * 40 + cq * 5 + 1];
    float w2 = Ws[k * 40 + cq * 5 + 2];
    float w3 = Ws[k * 40 + cq * 5 + 3];
    float w4 = Ws[k * 40 + cq * 5 + 4];
    a[0][0] = fmaf(xv.x, w0, a[0][0]); a[0][1] = fmaf(xv.x, w1, a[0][1]);
    a[0][2] = fmaf(xv.x, w2, a[0][2]); a[0][3] = fmaf(xv.x, w3, a[0][3]);
    a[0][4] = fmaf(xv.x, w4, a[0][4]);
    a[1][0] = fmaf(xv.y, w0, a[1][0]); a[1][1] = fmaf(xv.y, w1, a[1][1]);
    a[1][2] = fmaf(xv.y, w2, a[1][2]); a[1][3] = fmaf(xv.y, w3, a[1][3]);
    a[1][4] = fmaf(xv.y, w4, a[1][4]);
    a[2][0] = fmaf(xv.z, w0, a[2][0]); a[2][1] = fmaf(xv.z, w1, a[2][1]);
    a[2][2] = fmaf(xv.z, w2, a[2][2]); a[2][3] = fmaf(xv.z, w3, a[2][3]);
    a[2][4] = fmaf(xv.z, w4, a[2][4]);
    a[3][0] = fmaf(xv.w, w0, a[3][0]); a[3][1] = fmaf(xv.w, w1, a[3][1]);
    a[3][2] = fmaf(xv.w, w2, a[3][2]); a[3][3] = fmaf(xv.w, w3, a[3][3]);
    a[3][4] = fmaf(xv.w, w4, a[3][4]);
  }

  #pragma unroll
  for (int i = 0; i < 4; ++i) {
    int grow = row0 + rq * 4 + i;
    if (grow < NN) {
      float dv = dinv[grow];
      #pragma unroll
      for (int j = 0; j < 5; ++j)
        g2[(size_t)grow * 40 + cq * 5 + j] = (_Float16)(a[i][j] * dv);
    }
  }
}

// ---------------- gather layer2 (fused epilogue): out = (g2[c]+Σg2[src])·dinv[c] + b2 ----------------
__global__ __launch_bounds__(320) void k_gather2(const int* __restrict__ row_ptr, const int* __restrict__ src,
                                                 const _Float16* __restrict__ g2, const float* __restrict__ dinv,
                                                 const float* __restrict__ b2, float* __restrict__ out) {
  int t = threadIdx.x;
  int local = t / 10;
  int grp = t - local * 10;
  int node = blockIdx.x * 32 + local;
  if (node >= NN) return;
  int q = grp * 4;
  int beg = row_ptr[node], end = row_ptr[node + 1];
  half4 sv = *reinterpret_cast<const half4*>(&g2[(size_t)node * 40 + q]);  // self loop
  float4 acc = make_float4((float)sv.x, (float)sv.y, (float)sv.z, (float)sv.w);
  int e = beg;
  for (; e + 3 < end; e += 4) {
    int s0 = src[e], s1 = src[e + 1], s2 = src[e + 2], s3 = src[e + 3];
    half4 v0 = *reinterpret_cast<const half4*>(&g2[(size_t)s0 * 40 + q]);
    half4 v1 = *reinterpret_cast<const half4*>(&g2[(size_t)s1 * 40 + q]);
    half4 v2 = *reinterpret_cast<const half4*>(&g2[(size_t)s2 * 40 + q]);
    half4 v3 = *reinterpret_cast<const half4*>(&g2[(size_t)s3 * 40 + q]);
    acc.x += ((float)v0.x + (float)v1.x) + ((float)v2.x + (float)v3.x);
    acc.y += ((float)v0.y + (float)v1.y) + ((float)v2.y + (float)v3.y);
    acc.z += ((float)v0.z + (float)v1.z) + ((float)v2.z + (float)v3.z);
    acc.w += ((float)v0.w + (float)v1.w) + ((float)v2.w + (float)v3.w);
  }
  for (; e < end; ++e) {
    int s0 = src[e];
    half4 v0 = *reinterpret_cast<const half4*>(&g2[(size_t)s0 * 40 + q]);
    acc.x += (float)v0.x; acc.y += (float)v0.y; acc.z += (float)v0.z; acc.w += (float)v0.w;
  }
  float dv = dinv[node];
  float4 bv = *reinterpret_cast<const float4*>(&b2[q]);
  float4 o;
  o.x = acc.x * dv + bv.x; o.y = acc.y * dv + bv.y;
  o.z = acc.z * dv + bv.z; o.w = acc.w * dv + bv.w;
  *reinterpret_cast<float4*>(&out[(size_t)node * 40 + q]) = o;
}

extern "C" void kernel_launch(void* const* d_in, const int* in_sizes, int n_in,
                              void* d_out, int out_size, void* d_ws, size_t ws_size,
                              hipStream_t stream) {
  const float* x  = (const float*)d_in[0];
  const int*   ei = (const int*)d_in[1];       // row = ei, col = ei + EE
  const float* W1 = (const float*)d_in[2];
  const float* b1 = (const float*)d_in[3];
  const float* W2 = (const float*)d_in[4];
  const float* b2 = (const float*)d_in[5];
  float* out = (float*)d_out;

  const int* row = ei;
  const int* col = ei + EE;

  // workspace layout (4B units unless noted)
  float* ws      = (float*)d_ws;
  float* dinv    = ws;                          // 100352 f32
  int*   row_ptr = (int*)(ws + 100352);         // 100352 (needs NN+1)
  int*   bptr    = row_ptr + 100352;            // 512 (needs NB+1)
  int*   bcnt    = bptr + 512;                  // 512
  int*   bcur    = bcnt + 512;                  // 512
  int*   src     = bcur + 512;                  // 1200128
  _Float16* g1   = (_Float16*)(src + 1200128);  // 6.4M halves = 12.8 MB
  float* hid     = (float*)((char*)g1 + 12800000);  // 6.4M f32 = 25.6 MB
  _Float16* g2   = g1;                          // reuse (g1 dead after gather1); 4M halves = 8 MB
  int*   binned  = (int*)g1;                    // 1.2M ints, aliases g1 (dead before gemm1)

  // CSR build (bucketed counting sort) + dinv
  k_zero_b <<<2, 256, 0, stream>>>(bcnt);
  k_binhist<<<BIN_BLK, 256, 0, stream>>>(col, bcnt);
  k_binscan<<<1, 512, 0, stream>>>(bcnt, bptr, bcur, row_ptr);
  k_binfill<<<BIN_BLK, 256, 0, stream>>>(row, col, bcur, binned);
  k_build2 <<<NB, 256, 0, stream>>>(binned, bptr, row_ptr, src, dinv);

  // layer 1
  k_gemm1  <<<(NN + 63) / 64, 256, 0, stream>>>(x, W1, dinv, g1);
  k_gather1<<<(NN + 15) / 16, 256, 0, stream>>>(row_ptr, src, g1, dinv, b1, hid);

  // layer 2
  k_gemm2  <<<(NN + 127) / 128, 256, 0, stream>>>(hid, W2, dinv, g2);
  k_gather2<<<(NN + 31) / 32, 320, 0, stream>>>(row_ptr, src, g2, dinv, b2, out);
}

// Round 6
// 228.252 us; speedup vs baseline: 8.7384x; 1.0766x over previous
//
#include <hip/hip_runtime.h>

#define NN 100000
#define EE 1200000
#define NB 391          // ceil(NN/256) buckets of 256 nodes
#define EPB 4096        // edges per block in binning kernels
#define BIN_BLK 293     // ceil(EE/EPB)

typedef _Float16 half4 __attribute__((ext_vector_type(4)));
typedef _Float16 half8 __attribute__((ext_vector_type(8)));
typedef float    f32x4 __attribute__((ext_vector_type(4)));

// ---------------- zero bucket counters ----------------
__global__ __launch_bounds__(256) void k_zero_b(int* __restrict__ bcnt) {
  int i = blockIdx.x * 256 + threadIdx.x;
  if (i < NB) bcnt[i] = 0;
}

// ---------------- bucket histogram (LDS-aggregated) ----------------
__global__ __launch_bounds__(256) void k_binhist(const int* __restrict__ col, int* __restrict__ bcnt) {
  __shared__ int lh[NB];
  int t = threadIdx.x;
  for (int i = t; i < NB; i += 256) lh[i] = 0;
  __syncthreads();
  int base = blockIdx.x * EPB;
  #pragma unroll
  for (int i = 0; i < 16; ++i) {
    int e = base + i * 256 + t;
    if (e < EE) atomicAdd(&lh[col[e] >> 8], 1);
  }
  __syncthreads();
  for (int i = t; i < NB; i += 256) {
    int v = lh[i];
    if (v) atomicAdd(&bcnt[i], v);
  }
}

// ---------------- scan bucket counts -> bptr, init cursors ----------------
__global__ __launch_bounds__(512) void k_binscan(const int* __restrict__ bcnt, int* __restrict__ bptr,
                                                 int* __restrict__ bcur, int* __restrict__ row_ptr) {
  __shared__ int sm[512];
  int t = threadIdx.x;
  int v = (t < NB) ? bcnt[t] : 0;
  sm[t] = v;
  __syncthreads();
  for (int off = 1; off < 512; off <<= 1) {
    int u = (t >= off) ? sm[t - off] : 0;
    __syncthreads();
    sm[t] += u;
    __syncthreads();
  }
  int excl = sm[t] - v;
  if (t < NB) { bptr[t] = excl; bcur[t] = excl; }
  if (t == 0) { bptr[NB] = EE; row_ptr[NN] = EE; }
}

// ---------------- bucket fill: binned[p] = (row<<8)|(col&255), grouped by bucket ----------------
__global__ __launch_bounds__(256) void k_binfill(const int* __restrict__ row, const int* __restrict__ col,
                                                 int* __restrict__ bcur, int* __restrict__ binned) {
  __shared__ int lh[NB];
  __shared__ int lbase[NB];
  int t = threadIdx.x;
  for (int i = t; i < NB; i += 256) lh[i] = 0;
  __syncthreads();
  int base = blockIdx.x * EPB;
  #pragma unroll
  for (int i = 0; i < 16; ++i) {
    int e = base + i * 256 + t;
    if (e < EE) atomicAdd(&lh[col[e] >> 8], 1);
  }
  __syncthreads();
  // reserve contiguous global ranges per bucket; reset LDS cursors
  for (int i = t; i < NB; i += 256) {
    int v = lh[i];
    lbase[i] = v ? atomicAdd(&bcur[i], v) : 0;
  }
  __syncthreads();
  for (int i = t; i < NB; i += 256) lh[i] = 0;   // reuse as local cursor
  __syncthreads();
  #pragma unroll
  for (int i = 0; i < 16; ++i) {
    int e = base + i * 256 + t;
    if (e < EE) {
      int c = col[e];
      int b = c >> 8;
      int p = lbase[b] + atomicAdd(&lh[b], 1);
      binned[p] = (row[e] << 8) | (c & 255);
    }
  }
}

// ---------------- per-bucket CSR build: row_ptr, src, dinv (all bucket-local) ----------------
__global__ __launch_bounds__(256) void k_build2(const int* __restrict__ binned, const int* __restrict__ bptr,
                                                int* __restrict__ row_ptr, int* __restrict__ src,
                                                float* __restrict__ dinv) {
  __shared__ int cnt[256];
  __shared__ int sm[256];
  __shared__ int cur[256];
  int t = threadIdx.x;
  int b = blockIdx.x;
  int nb0 = b << 8;
  int nnode = NN - nb0 < 256 ? NN - nb0 : 256;
  int ebeg = bptr[b], eend = bptr[b + 1];
  cnt[t] = 0;
  __syncthreads();
  for (int e = ebeg + t; e < eend; e += 256)
    atomicAdd(&cnt[binned[e] & 255], 1);
  __syncthreads();
  int v = cnt[t];
  sm[t] = v;
  __syncthreads();
  for (int off = 1; off < 256; off <<= 1) {
    int u = (t >= off) ? sm[t - off] : 0;
    __syncthreads();
    sm[t] += u;
    __syncthreads();
  }
  int excl = sm[t] - v;
  if (t < nnode) {
    row_ptr[nb0 + t] = ebeg + excl;
    dinv[nb0 + t] = rsqrtf((float)v + 1.0f);   // deg = in-count + self-loop
  }
  cur[t] = excl;
  __syncthreads();
  for (int e = ebeg + t; e < eend; e += 256) {
    int rc = binned[e];
    int cl = rc & 255;
    int p = ebeg + atomicAdd(&cur[cl], 1);
    src[p] = rc >> 8;
  }
}

// ---------------- GEMM1 (MFMA f16): g = fp16((x @ W1) * dinv[row]) ----------------
// 64 rows/block, 4 waves; wave w -> rows w*16..w*16+15, all 64 cols (4 n-tiles), K=128 (4 k-steps).
// xh[64][136] halves: row stride 272 B (16B-aligned, bank-stagger 4 -> 2-way free on b128 reads).
__global__ __launch_bounds__(256) void k_gemm1(const float* __restrict__ x, const float* __restrict__ W,
                                               const float* __restrict__ dinv, _Float16* __restrict__ g) {
  __shared__ _Float16 xh[64 * 136];   // 17.4 KB
  __shared__ _Float16 Wt[64 * 136];   // 17.4 KB, transposed: Wt[n][k]
  const int t = threadIdx.x;
  const int row0 = blockIdx.x * 64;

  // stage W transposed -> f16 (coalesced float4 reads; one-time scalar LDS writes)
  #pragma unroll
  for (int p = 0; p < 8; ++p) {
    int idx = t + p * 256;
    int k = idx >> 4;
    int n4 = (idx & 15) << 2;
    float4 v = *reinterpret_cast<const float4*>(&W[k * 64 + n4]);
    Wt[(n4 + 0) * 136 + k] = (_Float16)v.x;
    Wt[(n4 + 1) * 136 + k] = (_Float16)v.y;
    Wt[(n4 + 2) * 136 + k] = (_Float16)v.z;
    Wt[(n4 + 3) * 136 + k] = (_Float16)v.w;
  }
  // stage x rows -> f16 (32 B/lane coalesced reads, b128 conflict-free LDS writes)
  #pragma unroll
  for (int p = 0; p < 4; ++p) {
    int idx = t + p * 256;          // 0..1023
    int r = idx >> 4;               // 0..63
    int k8 = idx & 15;              // 8-half group
    int grow = row0 + r;
    half8 h = {0, 0, 0, 0, 0, 0, 0, 0};
    if (grow < NN) {
      float4 a0 = *reinterpret_cast<const float4*>(&x[(size_t)grow * 128 + k8 * 8]);
      float4 a1 = *reinterpret_cast<const float4*>(&x[(size_t)grow * 128 + k8 * 8 + 4]);
      h[0] = (_Float16)a0.x; h[1] = (_Float16)a0.y; h[2] = (_Float16)a0.z; h[3] = (_Float16)a0.w;
      h[4] = (_Float16)a1.x; h[5] = (_Float16)a1.y; h[6] = (_Float16)a1.z; h[7] = (_Float16)a1.w;
    }
    *reinterpret_cast<half8*>(&xh[r * 136 + k8 * 8]) = h;
  }
  __syncthreads();

  const int w = t >> 6;      // wave 0..3
  const int l = t & 63;
  const int lrow = l & 15;   // A row / B col / C col
  const int kg = l >> 4;     // k-group 0..3

  f32x4 z = {0.0f, 0.0f, 0.0f, 0.0f};
  f32x4 acc[4];
  acc[0] = z; acc[1] = z; acc[2] = z; acc[3] = z;

  const _Float16* xb = &xh[(w * 16 + lrow) * 136 + kg * 8];
  #pragma unroll
  for (int s = 0; s < 4; ++s) {     // K=128, 32 per step
    half8 a = *reinterpret_cast<const half8*>(xb + s * 32);
    #pragma unroll
    for (int nt = 0; nt < 4; ++nt) {
      half8 b = *reinterpret_cast<const half8*>(&Wt[(nt * 16 + lrow) * 136 + kg * 8 + s * 32]);
      acc[nt] = __builtin_amdgcn_mfma_f32_16x16x32_f16(a, b, acc[nt], 0, 0, 0);
    }
  }

  // epilogue: C/D layout col=lane&15, row=(lane>>4)*4+reg (m89-verified)
  float dv[4];
  #pragma unroll
  for (int r = 0; r < 4; ++r) {
    int grow = row0 + w * 16 + kg * 4 + r;
    dv[r] = (grow < NN) ? dinv[grow] : 0.0f;
  }
  #pragma unroll
  for (int nt = 0; nt < 4; ++nt)
    #pragma unroll
    for (int r = 0; r < 4; ++r) {
      int grow = row0 + w * 16 + kg * 4 + r;
      if (grow < NN)
        g[(size_t)grow * 64 + nt * 16 + lrow] = (_Float16)(acc[nt][r] * dv[r]);
    }
}

// ---------------- gather layer1 (fused epilogue): hid = fp16(lrelu((g[c]+Σg[src])·dinv[c] + b1)) ----------------
__global__ __launch_bounds__(256) void k_gather1(const int* __restrict__ row_ptr, const int* __restrict__ src,
                                                 const _Float16* __restrict__ g, const float* __restrict__ dinv,
                                                 const float* __restrict__ b1, _Float16* __restrict__ hid) {
  int t = threadIdx.x;
  int node = blockIdx.x * 16 + (t >> 4);
  if (node >= NN) return;
  int q = (t & 15) << 2;
  int beg = row_ptr[node], end = row_ptr[node + 1];
  half4 sv = *reinterpret_cast<const half4*>(&g[(size_t)node * 64 + q]);   // self loop
  float4 acc = make_float4((float)sv.x, (float)sv.y, (float)sv.z, (float)sv.w);
  int e = beg;
  for (; e + 3 < end; e += 4) {
    int s0 = src[e], s1 = src[e + 1], s2 = src[e + 2], s3 = src[e + 3];
    half4 v0 = *reinterpret_cast<const half4*>(&g[(size_t)s0 * 64 + q]);
    half4 v1 = *reinterpret_cast<const half4*>(&g[(size_t)s1 * 64 + q]);
    half4 v2 = *reinterpret_cast<const half4*>(&g[(size_t)s2 * 64 + q]);
    half4 v3 = *reinterpret_cast<const half4*>(&g[(size_t)s3 * 64 + q]);
    acc.x += ((float)v0.x + (float)v1.x) + ((float)v2.x + (float)v3.x);
    acc.y += ((float)v0.y + (float)v1.y) + ((float)v2.y + (float)v3.y);
    acc.z += ((float)v0.z + (float)v1.z) + ((float)v2.z + (float)v3.z);
    acc.w += ((float)v0.w + (float)v1.w) + ((float)v2.w + (float)v3.w);
  }
  for (; e < end; ++e) {
    int s0 = src[e];
    half4 v0 = *reinterpret_cast<const half4*>(&g[(size_t)s0 * 64 + q]);
    acc.x += (float)v0.x; acc.y += (float)v0.y; acc.z += (float)v0.z; acc.w += (float)v0.w;
  }
  float dv = dinv[node];
  float4 bv = *reinterpret_cast<const float4*>(&b1[q]);
  float4 o;
  o.x = acc.x * dv + bv.x; o.y = acc.y * dv + bv.y;
  o.z = acc.z * dv + bv.z; o.w = acc.w * dv + bv.w;
  o.x = o.x > 0.f ? o.x : 0.01f * o.x;
  o.y = o.y > 0.f ? o.y : 0.01f * o.y;
  o.z = o.z > 0.f ? o.z : 0.01f * o.z;
  o.w = o.w > 0.f ? o.w : 0.01f * o.w;
  half4 ho;
  ho.x = (_Float16)o.x; ho.y = (_Float16)o.y; ho.z = (_Float16)o.z; ho.w = (_Float16)o.w;
  *reinterpret_cast<half4*>(&hid[(size_t)node * 64 + q]) = ho;
}

// ---------------- GEMM2 (MFMA f16): g2 = fp16((hid @ W2) * dinv[row]), N=40 padded to 48 ----------------
__global__ __launch_bounds__(256) void k_gemm2(const _Float16* __restrict__ hid, const float* __restrict__ W,
                                               const float* __restrict__ dinv, _Float16* __restrict__ g2) {
  __shared__ _Float16 xh[64 * 72];   // 9.2 KB, row stride 144 B
  __shared__ _Float16 Wt[48 * 72];   // 6.9 KB, transposed + zero-padded cols 40..47
  const int t = threadIdx.x;
  const int row0 = blockIdx.x * 64;

  #pragma unroll
  for (int p = 0; p < 12; ++p) {     // 48*64 = 3072 slots
    int idx = t + p * 256;
    int n = idx >> 6, k = idx & 63;
    _Float16 v = (_Float16)0.0f;
    if (n < 40) v = (_Float16)W[k * 40 + n];
    Wt[n * 72 + k] = v;
  }
  #pragma unroll
  for (int p = 0; p < 2; ++p) {      // 64 rows x 8 half8-groups
    int idx = t + p * 256;
    int r = idx >> 3, k8 = idx & 7;
    int grow = row0 + r;
    half8 h = {0, 0, 0, 0, 0, 0, 0, 0};
    if (grow < NN) h = *reinterpret_cast<const half8*>(&hid[(size_t)grow * 64 + k8 * 8]);
    *reinterpret_cast<half8*>(&xh[r * 72 + k8 * 8]) = h;
  }
  __syncthreads();

  const int w = t >> 6;
  const int l = t & 63;
  const int lrow = l & 15;
  const int kg = l >> 4;

  f32x4 z = {0.0f, 0.0f, 0.0f, 0.0f};
  f32x4 acc[3];
  acc[0] = z; acc[1] = z; acc[2] = z;

  const _Float16* xb = &xh[(w * 16 + lrow) * 72 + kg * 8];
  #pragma unroll
  for (int s = 0; s < 2; ++s) {      // K=64, 32 per step
    half8 a = *reinterpret_cast<const half8*>(xb + s * 32);
    #pragma unroll
    for (int nt = 0; nt < 3; ++nt) {
      half8 b = *reinterpret_cast<const half8*>(&Wt[(nt * 16 + lrow) * 72 + kg * 8 + s * 32]);
      acc[nt] = __builtin_amdgcn_mfma_f32_16x16x32_f16(a, b, acc[nt], 0, 0, 0);
    }
  }

  float dv[4];
  #pragma unroll
  for (int r = 0; r < 4; ++r) {
    int grow = row0 + w * 16 + kg * 4 + r;
    dv[r] = (grow < NN) ? dinv[grow] : 0.0f;
  }
  #pragma unroll
  for (int nt = 0; nt < 3; ++nt) {
    int colv = nt * 16 + lrow;
    #pragma unroll
    for (int r = 0; r < 4; ++r) {
      int grow = row0 + w * 16 + kg * 4 + r;
      if (grow < NN && colv < 40)
        g2[(size_t)grow * 40 + colv] = (_Float16)(acc[nt][r] * dv[r]);
    }
  }
}

// ---------------- gather layer2 (fused epilogue): out = (g2[c]+Σg2[src])·dinv[c] + b2 ----------------
__global__ __launch_bounds__(320) void k_gather2(const int* __restrict__ row_ptr, const int* __restrict__ src,
                                                 const _Float16* __restrict__ g2, const float* __restrict__ dinv,
                                                 const float* __restrict__ b2, float* __restrict__ out) {
  int t = threadIdx.x;
  int local = t / 10;
  int grp = t - local * 10;
  int node = blockIdx.x * 32 + local;
  if (node >= NN) return;
  int q = grp * 4;
  int beg = row_ptr[node], end = row_ptr[node + 1];
  half4 sv = *reinterpret_cast<const half4*>(&g2[(size_t)node * 40 + q]);  // self loop
  float4 acc = make_float4((float)sv.x, (float)sv.y, (float)sv.z, (float)sv.w);
  int e = beg;
  for (; e + 3 < end; e += 4) {
    int s0 = src[e], s1 = src[e + 1], s2 = src[e + 2], s3 = src[e + 3];
    half4 v0 = *reinterpret_cast<const half4*>(&g2[(size_t)s0 * 40 + q]);
    half4 v1 = *reinterpret_cast<const half4*>(&g2[(size_t)s1 * 40 + q]);
    half4 v2 = *reinterpret_cast<const half4*>(&g2[(size_t)s2 * 40 + q]);
    half4 v3 = *reinterpret_cast<const half4*>(&g2[(size_t)s3 * 40 + q]);
    acc.x += ((float)v0.x + (float)v1.x) + ((float)v2.x + (float)v3.x);
    acc.y += ((float)v0.y + (float)v1.y) + ((float)v2.y + (float)v3.y);
    acc.z += ((float)v0.z + (float)v1.z) + ((float)v2.z + (float)v3.z);
    acc.w += ((float)v0.w + (float)v1.w) + ((float)v2.w + (float)v3.w);
  }
  for (; e < end; ++e) {
    int s0 = src[e];
    half4 v0 = *reinterpret_cast<const half4*>(&g2[(size_t)s0 * 40 + q]);
    acc.x += (float)v0.x; acc.y += (float)v0.y; acc.z += (float)v0.z; acc.w += (float)v0.w;
  }
  float dv = dinv[node];
  float4 bv = *reinterpret_cast<const float4*>(&b2[q]);
  float4 o;
  o.x = acc.x * dv + bv.x; o.y = acc.y * dv + bv.y;
  o.z = acc.z * dv + bv.z; o.w = acc.w * dv + bv.w;
  *reinterpret_cast<float4*>(&out[(size_t)node * 40 + q]) = o;
}

extern "C" void kernel_launch(void* const* d_in, const int* in_sizes, int n_in,
                              void* d_out, int out_size, void* d_ws, size_t ws_size,
                              hipStream_t stream) {
  const float* x  = (const float*)d_in[0];
  const int*   ei = (const int*)d_in[1];       // row = ei, col = ei + EE
  const float* W1 = (const float*)d_in[2];
  const float* b1 = (const float*)d_in[3];
  const float* W2 = (const float*)d_in[4];
  const float* b2 = (const float*)d_in[5];
  float* out = (float*)d_out;

  const int* row = ei;
  const int* col = ei + EE;

  // workspace layout (4B units unless noted)
  float* ws      = (float*)d_ws;
  float* dinv    = ws;                          // 100352 f32
  int*   row_ptr = (int*)(ws + 100352);         // 100352 (needs NN+1)
  int*   bptr    = row_ptr + 100352;            // 512 (needs NB+1)
  int*   bcnt    = bptr + 512;                  // 512
  int*   bcur    = bcnt + 512;                  // 512
  int*   src     = bcur + 512;                  // 1200128
  _Float16* g1   = (_Float16*)(src + 1200128);  // 6.4M halves = 12.8 MB
  _Float16* hid  = (_Float16*)((char*)g1 + 12800000);  // 6.4M halves = 12.8 MB
  _Float16* g2   = g1;                          // reuse (g1 dead after gather1); 4M halves = 8 MB
  int*   binned  = (int*)g1;                    // 1.2M ints, aliases g1 (dead before gemm1)

  // CSR build (bucketed counting sort) + dinv
  k_zero_b <<<2, 256, 0, stream>>>(bcnt);
  k_binhist<<<BIN_BLK, 256, 0, stream>>>(col, bcnt);
  k_binscan<<<1, 512, 0, stream>>>(bcnt, bptr, bcur, row_ptr);
  k_binfill<<<BIN_BLK, 256, 0, stream>>>(row, col, bcur, binned);
  k_build2 <<<NB, 256, 0, stream>>>(binned, bptr, row_ptr, src, dinv);

  // layer 1
  k_gemm1  <<<(NN + 63) / 64, 256, 0, stream>>>(x, W1, dinv, g1);
  k_gather1<<<(NN + 15) / 16, 256, 0, stream>>>(row_ptr, src, g1, dinv, b1, hid);

  // layer 2
  k_gemm2  <<<(NN + 63) / 64, 256, 0, stream>>>(hid, W2, dinv, g2);
  k_gather2<<<(NN + 31) / 32, 320, 0, stream>>>(row_ptr, src, g2, dinv, b2, out);
}